// Round 8
// baseline (665.947 us; speedup 1.0000x reference)
//
#include <hip/hip_runtime.h>
#include <math.h>

#define N_NODES 50000
#define N_EDGES 800000
#define HDIM 128
#define NLAYERS 4
#define LN_EPS 1e-5f
#define SEG 64          // CSR slots per node (P(deg>64) ~ 1e-19 for Poisson(16))
#define KBUCK 391       // buckets of 128 nodes: 391*128 = 50048 >= N_NODES
#define BINCAP 32       // LDS bin capacity per bucket per block (overflow path exact)
#define GCAP 2560       // global bucket capacity (mean 2046, +11 sigma)
#define EPB 2048        // edges per binA block

typedef __attribute__((ext_vector_type(8))) short short8;
typedef __attribute__((ext_vector_type(4))) float floatx4;

__device__ __forceinline__ ushort f2bf(float x) {
    unsigned b = __float_as_uint(x);
    unsigned r = b + 0x7fffu + ((b >> 16) & 1u);
    return (ushort)(r >> 16);
}
__device__ __forceinline__ float2 bf2f2(unsigned u) {
    return make_float2(__uint_as_float(u << 16), __uint_as_float(u & 0xffff0000u));
}

// ---------------- CSR build: two-phase LDS binning ----------------

// Phase A: bin edges by dst>>7 in LDS, drain per-bucket as contiguous bursts.
__global__ __launch_bounds__(256) void binA_kernel(const int* __restrict__ src,
                                                   const int* __restrict__ dst,
                                                   int* __restrict__ gcnt,
                                                   unsigned* __restrict__ gbuck) {
    __shared__ unsigned bins[KBUCK][BINCAP];
    __shared__ int bcnt[KBUCK];
    for (int i = threadIdx.x; i < KBUCK; i += 256) bcnt[i] = 0;
    __syncthreads();
    int base = blockIdx.x * EPB;
#pragma unroll
    for (int it = 0; it < EPB / 256; ++it) {
        int e = base + it * 256 + threadIdx.x;
        if (e < N_EDGES) {
            int s = src[e], d = dst[e];
            int bk = d >> 7;
            unsigned entry = ((unsigned)(d & 127) << 16) | (unsigned)s;
            int slot = atomicAdd(&bcnt[bk], 1);
            if (slot < BINCAP) {
                bins[bk][slot] = entry;
            } else {  // rare overflow: exact direct path
                int p = atomicAdd(&gcnt[bk], 1);
                if (p < GCAP) gbuck[(size_t)bk * GCAP + p] = entry;
            }
        }
    }
    __syncthreads();
    int wave = threadIdx.x >> 6, lane = threadIdx.x & 63;
    for (int bk = wave; bk < KBUCK; bk += 4) {
        int m = min(bcnt[bk], BINCAP);
        if (m == 0) continue;
        int p0 = 0;
        if (lane == 0) p0 = atomicAdd(&gcnt[bk], m);
        p0 = __shfl(p0, 0);
        if (lane < m && p0 + lane < GCAP)
            gbuck[(size_t)bk * GCAP + p0 + lane] = bins[bk][lane];
    }
}

// Phase B: per bucket, place edges into a 16KB LDS CSR window, stream out
// coalesced; fuse degree/isd/ind computation.
__global__ __launch_bounds__(256) void binB_kernel(const int* __restrict__ gcnt,
                                                   const unsigned* __restrict__ gbuck,
                                                   ushort* __restrict__ csr16,
                                                   int* __restrict__ degcnt,
                                                   float* __restrict__ isd,
                                                   float* __restrict__ ind) {
    __shared__ ushort win[128 * SEG];  // 16 KB
    __shared__ int cnt[128];
    int bk = blockIdx.x;
    for (int i = threadIdx.x; i < 128; i += 256) cnt[i] = 0;
    __syncthreads();
    int M = min(gcnt[bk], GCAP);
    for (int i = threadIdx.x; i < M; i += 256) {
        unsigned e = gbuck[(size_t)bk * GCAP + i];
        int dloc = e >> 16;
        int slot = atomicAdd(&cnt[dloc], 1);
        if (slot < SEG) win[dloc * SEG + slot] = (ushort)(e & 0xffffu);
    }
    __syncthreads();
    // stream window: 128*64 ushorts = 16 KB = 1024 uint4 (unused slots = garbage, never read)
    uint4* wg = (uint4*)win;
    uint4* outp = (uint4*)(csr16 + (size_t)bk * 128 * SEG);
    for (int i = threadIdx.x; i < 1024; i += 256) outp[i] = wg[i];
    for (int i = threadIdx.x; i < 128; i += 256) {
        int n = bk * 128 + i;
        if (n < N_NODES) {
            int dg = cnt[i];
            degcnt[n] = dg;
            float d = (float)dg + 1.0f;  // self-loop
            isd[n] = rsqrtf(d);
            ind[n] = 1.0f / d;
        }
    }
}

// ---------------- W -> MFMA B-fragment layout (bf16), once per launch ----------------
// idx = ((l*4 + s)*8 + t)*64 + lane; holds B[k=s*32+(lane>>4)*8+j][n=t*16+(lane&15)], j=0..7
__global__ __launch_bounds__(256) void bprep_kernel(const float* __restrict__ W,
                                                    ushort* __restrict__ bfrag) {
    int idx = blockIdx.x * 256 + threadIdx.x;
    if (idx >= NLAYERS * 4 * 8 * 64) return;
    int lane = idx & 63;
    int t = (idx >> 6) & 7;
    int s = (idx >> 9) & 3;
    int l = idx >> 11;
    int n = t * 16 + (lane & 15);
    int kb = s * 32 + (lane >> 4) * 8;
    const float* Wl = W + (size_t)l * HDIM * HDIM;
    union { uint4 q; ushort u[8]; } o;
#pragma unroll
    for (int j = 0; j < 8; ++j) o.u[j] = f2bf(Wl[(size_t)(kb + j) * HDIM + n]);
    *(uint4*)&bfrag[(size_t)idx * 8] = o.q;
}

// ---------------- GEMM: hw_bf16 = A @ W  via MFMA 16x16x32 bf16 ----------------
template <bool A_FP32>
__global__ __launch_bounds__(256) void gemm_mfma_kernel(const void* __restrict__ Av,
                                                        const ushort* __restrict__ bfrag,
                                                        ushort* __restrict__ out) {
    int wave = threadIdx.x >> 6, lane = threadIdx.x & 63;
    int quad = lane >> 4, mrow = lane & 15;
    int rowBase = blockIdx.x * 64 + wave * 16;
    int arow = rowBase + mrow;
    bool aok = arow < N_NODES;

    floatx4 acc[8];
#pragma unroll
    for (int t = 0; t < 8; ++t) acc[t] = (floatx4)0.f;

#pragma unroll
    for (int s = 0; s < 4; ++s) {
        union { short8 v; ushort u[8]; } af;
        if (A_FP32) {
            const float* A = (const float*)Av;
            if (aok) {
                const float* p = &A[(size_t)arow * HDIM + s * 32 + quad * 8];
#pragma unroll
                for (int j = 0; j < 8; ++j) af.u[j] = f2bf(p[j]);
            } else {
#pragma unroll
                for (int j = 0; j < 8; ++j) af.u[j] = 0;
            }
        } else {
            const ushort* A = (const ushort*)Av;
            if (aok) {
                af.v = *(const short8*)&A[(size_t)arow * HDIM + s * 32 + quad * 8];
            } else {
#pragma unroll
                for (int j = 0; j < 8; ++j) af.u[j] = 0;
            }
        }
#pragma unroll
        for (int t = 0; t < 8; ++t) {
            short8 bf = *(const short8*)&bfrag[(size_t)(((s * 8 + t) * 64) + lane) * 8];
            acc[t] = __builtin_amdgcn_mfma_f32_16x16x32_bf16(af.v, bf, acc[t], 0, 0, 0);
        }
    }
    // C/D layout: col = lane&15 (tile t), row = quad*4 + reg
#pragma unroll
    for (int t = 0; t < 8; ++t) {
#pragma unroll
        for (int r = 0; r < 4; ++r) {
            int row = rowBase + quad * 4 + r;
            if (row < N_NODES) out[(size_t)row * HDIM + t * 16 + mrow] = f2bf(acc[t][r]);
        }
    }
}

// ---------------- Fused aggregate + self-loop + bias + LN (+GELU / +head) ----------------
// One wave per node; lane owns 2 columns. Weight factored: isd[n] * sum(isd[s]*hw[s]).
__global__ __launch_bounds__(256) void agg_ln_kernel(
    const unsigned* __restrict__ hwu, const int* __restrict__ degcnt,
    const ushort* __restrict__ csr16, const float* __restrict__ isd,
    const float* __restrict__ ind, const float* __restrict__ conv_b,
    const float* __restrict__ ln_g, const float* __restrict__ ln_b,
    unsigned* __restrict__ hout_bf, float* __restrict__ hout_f32,
    const float* __restrict__ head_w, const float* __restrict__ head_b,
    float* __restrict__ scores, int final_layer) {
    int wave = threadIdx.x >> 6;
    int lane = threadIdx.x & 63;
    int n = blockIdx.x * 4 + wave;
    if (n >= N_NODES) return;
    int c = lane * 2;

    float2 hv = bf2f2(hwu[(size_t)n * 64 + lane]);
    float isd_n = isd[n];
    float ind_n = ind[n];
    int rs = n * SEG;
    int deg = min(degcnt[n], SEG);

    float ex = 0.f, ey = 0.f;
    {
        int m = deg;  // deg <= SEG = 64: single staging pass
        int sj = 0;
        float wj = 0.f;
        if (lane < m) {
            sj = (int)csr16[rs + lane];
            wj = isd[sj];
        }
        for (int j = 0; j < m; j += 8) {
            int s0 = __shfl(sj, j + 0), s1 = __shfl(sj, j + 1);
            int s2 = __shfl(sj, j + 2), s3 = __shfl(sj, j + 3);
            int s4 = __shfl(sj, j + 4), s5 = __shfl(sj, j + 5);
            int s6 = __shfl(sj, j + 6), s7 = __shfl(sj, j + 7);
            float w0 = __shfl(wj, j + 0), w1 = __shfl(wj, j + 1);
            float w2 = __shfl(wj, j + 2), w3 = __shfl(wj, j + 3);
            float w4 = __shfl(wj, j + 4), w5 = __shfl(wj, j + 5);
            float w6 = __shfl(wj, j + 6), w7 = __shfl(wj, j + 7);
            unsigned u0 = hwu[(size_t)s0 * 64 + lane];
            unsigned u1 = hwu[(size_t)s1 * 64 + lane];
            unsigned u2 = hwu[(size_t)s2 * 64 + lane];
            unsigned u3 = hwu[(size_t)s3 * 64 + lane];
            unsigned u4 = hwu[(size_t)s4 * 64 + lane];
            unsigned u5 = hwu[(size_t)s5 * 64 + lane];
            unsigned u6 = hwu[(size_t)s6 * 64 + lane];
            unsigned u7 = hwu[(size_t)s7 * 64 + lane];
            float2 v0 = bf2f2(u0), v1 = bf2f2(u1), v2 = bf2f2(u2), v3 = bf2f2(u3);
            float2 v4 = bf2f2(u4), v5 = bf2f2(u5), v6 = bf2f2(u6), v7 = bf2f2(u7);
            ex = fmaf(v0.x, w0, ex); ey = fmaf(v0.y, w0, ey);
            ex = fmaf(v1.x, w1, ex); ey = fmaf(v1.y, w1, ey);
            ex = fmaf(v2.x, w2, ex); ey = fmaf(v2.y, w2, ey);
            ex = fmaf(v3.x, w3, ex); ey = fmaf(v3.y, w3, ey);
            ex = fmaf(v4.x, w4, ex); ey = fmaf(v4.y, w4, ey);
            ex = fmaf(v5.x, w5, ex); ey = fmaf(v5.y, w5, ey);
            ex = fmaf(v6.x, w6, ex); ey = fmaf(v6.y, w6, ey);
            ex = fmaf(v7.x, w7, ex); ey = fmaf(v7.y, w7, ey);
        }
    }
    float2 cb = *(const float2*)&conv_b[c];
    float ax = fmaf(ex, isd_n, fmaf(hv.x, ind_n, cb.x));
    float ay = fmaf(ey, isd_n, fmaf(hv.y, ind_n, cb.y));

    // LayerNorm across 128 columns of the wave (fp32)
    float sum = ax + ay;
#pragma unroll
    for (int o = 32; o; o >>= 1) sum += __shfl_xor(sum, o);
    float mu = sum * (1.0f / HDIM);
    float dx = ax - mu, dy = ay - mu;
    float vs = dx * dx + dy * dy;
#pragma unroll
    for (int o = 32; o; o >>= 1) vs += __shfl_xor(vs, o);
    float rstd = rsqrtf(vs * (1.0f / HDIM) + LN_EPS);
    float2 g = *(const float2*)&ln_g[c];
    float2 b = *(const float2*)&ln_b[c];
    float yx = fmaf(dx * rstd, g.x, b.x);
    float yy = fmaf(dy * rstd, g.y, b.y);

    if (!final_layer) {
        yx = 0.5f * yx * (1.0f + erff(yx * 0.70710678118654752f));
        yy = 0.5f * yy * (1.0f + erff(yy * 0.70710678118654752f));
        hout_bf[(size_t)n * 64 + lane] = (unsigned)f2bf(yx) | ((unsigned)f2bf(yy) << 16);
    } else {
        *(float2*)&hout_f32[(size_t)n * HDIM + c] = make_float2(yx, yy);
        float2 hwv = *(const float2*)&head_w[c];
        float p = yx * hwv.x + yy * hwv.y;
#pragma unroll
        for (int o = 32; o; o >>= 1) p += __shfl_xor(p, o);
        if (lane == 0) scores[n] = p + head_b[0];
    }
}

// ---------------- host ----------------

extern "C" void kernel_launch(void* const* d_in, const int* in_sizes, int n_in,
                              void* d_out, int out_size, void* d_ws, size_t ws_size,
                              hipStream_t stream) {
    const float* x      = (const float*)d_in[0];
    const int*   eidx   = (const int*)d_in[1];
    const float* conv_w = (const float*)d_in[2];
    const float* conv_b = (const float*)d_in[3];
    const float* ln_g   = (const float*)d_in[4];
    const float* ln_b   = (const float*)d_in[5];
    const float* head_w = (const float*)d_in[6];
    const float* head_b = (const float*)d_in[7];
    float* out = (float*)d_out;  // [N scores][N*H h]

    const int* src = eidx;
    const int* dst = eidx + N_EDGES;

    char* ws = (char*)d_ws;
    size_t o = 0;
    auto alloc = [&](size_t elems) {  // elems of 4 bytes
        void* p = ws + o * 4;
        o += (elems + 15) & ~(size_t)15;
        return p;
    };
    int*      gcnt     = (int*)alloc(KBUCK);
    unsigned* gbuck    = (unsigned*)alloc((size_t)KBUCK * GCAP);
    int*      degcnt   = (int*)alloc(N_NODES);
    float*    isd      = (float*)alloc(N_NODES);
    float*    ind      = (float*)alloc(N_NODES);
    ushort*   csr16    = (ushort*)alloc((size_t)KBUCK * 128 * SEG / 2);
    ushort*   bfrag    = (ushort*)alloc(NLAYERS * 4 * 8 * 64 * 8 / 2);
    unsigned* hw       = (unsigned*)alloc((size_t)N_NODES * 64);   // bf16 N x 128
    unsigned* hbuf     = (unsigned*)alloc((size_t)N_NODES * 64);   // bf16 N x 128

    hipMemsetAsync(gcnt, 0, KBUCK * sizeof(int), stream);
    int nA = (N_EDGES + EPB - 1) / EPB;  // 391 blocks
    binA_kernel<<<nA, 256, 0, stream>>>(src, dst, gcnt, gbuck);
    binB_kernel<<<KBUCK, 256, 0, stream>>>(gcnt, gbuck, csr16, degcnt, isd, ind);
    bprep_kernel<<<(NLAYERS * 4 * 8 * 64 + 255) / 256, 256, 0, stream>>>(conv_w, bfrag);

    const void* hin = (const void*)x;
    for (int l = 0; l < NLAYERS; ++l) {
        const ushort* bl = bfrag + (size_t)l * 4 * 8 * 64 * 8;
        if (l == 0)
            gemm_mfma_kernel<true><<<(N_NODES + 63) / 64, 256, 0, stream>>>(hin, bl, (ushort*)hw);
        else
            gemm_mfma_kernel<false><<<(N_NODES + 63) / 64, 256, 0, stream>>>(hin, bl, (ushort*)hw);
        int fin = (l == NLAYERS - 1) ? 1 : 0;
        agg_ln_kernel<<<(N_NODES + 3) / 4, 256, 0, stream>>>(
            hw, degcnt, csr16, isd, ind,
            conv_b + (size_t)l * HDIM, ln_g + (size_t)l * HDIM, ln_b + (size_t)l * HDIM,
            hbuf, out + N_NODES, head_w, head_b, out, fin);
        hin = (const void*)hbuf;
    }
}

// Round 9
// 349.808 us; speedup vs baseline: 1.9038x; 1.9038x over previous
//
#include <hip/hip_runtime.h>
#include <math.h>

#define N_NODES 50000
#define N_EDGES 800000
#define HDIM 128
#define NLAYERS 4
#define LN_EPS 1e-5f
#define EQUARTER (N_EDGES / 4)
#define SEG 64   // CSR slots per node (P(deg>64) ~ 1e-19 for Poisson(16))
#define FILLB ((EQUARTER + 255) / 256)   // 782 fill blocks
#define GEMMB ((N_NODES + 63) / 64)      // 782 gemm blocks

typedef __attribute__((ext_vector_type(8))) short short8;
typedef __attribute__((ext_vector_type(4))) float floatx4;

__device__ __forceinline__ ushort f2bf(float x) {
    unsigned b = __float_as_uint(x);
    unsigned r = b + 0x7fffu + ((b >> 16) & 1u);
    return (ushort)(r >> 16);
}
__device__ __forceinline__ float2 bf2f2(unsigned u) {
    return make_float2(__uint_as_float(u << 16), __uint_as_float(u & 0xffff0000u));
}

// ---------------- CSR build: padded segments, single scattered pass ----------------

__device__ __forceinline__ void fill_body(int bid, int tid, const int* __restrict__ src,
                                          const int* __restrict__ dst, int* __restrict__ cnt,
                                          ushort* __restrict__ csr16) {
    int t = bid * 256 + tid;
    if (t >= EQUARTER) return;
    int s0 = src[t],                d0 = dst[t];
    int s1 = src[t + EQUARTER],     d1 = dst[t + EQUARTER];
    int s2 = src[t + 2 * EQUARTER], d2 = dst[t + 2 * EQUARTER];
    int s3 = src[t + 3 * EQUARTER], d3 = dst[t + 3 * EQUARTER];
    int p0 = atomicAdd(&cnt[d0], 1);
    int p1 = atomicAdd(&cnt[d1], 1);
    int p2 = atomicAdd(&cnt[d2], 1);
    int p3 = atomicAdd(&cnt[d3], 1);
    if (p0 < SEG) csr16[d0 * SEG + p0] = (ushort)s0;
    if (p1 < SEG) csr16[d1 * SEG + p1] = (ushort)s1;
    if (p2 < SEG) csr16[d2 * SEG + p2] = (ushort)s2;
    if (p3 < SEG) csr16[d3 * SEG + p3] = (ushort)s3;
}

__global__ __launch_bounds__(256) void isd_kernel(const int* __restrict__ cnt,
                                                  float* __restrict__ isd,
                                                  float* __restrict__ ind) {
    int i = blockIdx.x * 256 + threadIdx.x;
    if (i < N_NODES) {
        float d = (float)cnt[i] + 1.0f;  // self-loop
        isd[i] = rsqrtf(d);
        ind[i] = 1.0f / d;
    }
}

// ---------------- W -> MFMA B-fragment layout (bf16), once per launch ----------------
__global__ __launch_bounds__(256) void bprep_kernel(const float* __restrict__ W,
                                                    ushort* __restrict__ bfrag) {
    int idx = blockIdx.x * 256 + threadIdx.x;
    if (idx >= NLAYERS * 4 * 8 * 64) return;
    int lane = idx & 63;
    int t = (idx >> 6) & 7;
    int s = (idx >> 9) & 3;
    int l = idx >> 11;
    int n = t * 16 + (lane & 15);
    int kb = s * 32 + (lane >> 4) * 8;
    const float* Wl = W + (size_t)l * HDIM * HDIM;
    union { uint4 q; ushort u[8]; } o;
#pragma unroll
    for (int j = 0; j < 8; ++j) o.u[j] = f2bf(Wl[(size_t)(kb + j) * HDIM + n]);
    *(uint4*)&bfrag[(size_t)idx * 8] = o.q;
}

// ---------------- GEMM body: hw_bf16 = A @ W  via MFMA 16x16x32 bf16 ----------------
template <bool A_FP32>
__device__ __forceinline__ void gemm_body(int bid, int tid, const void* __restrict__ Av,
                                          const ushort* __restrict__ bfrag,
                                          ushort* __restrict__ out) {
    int wave = tid >> 6, lane = tid & 63;
    int quad = lane >> 4, mrow = lane & 15;
    int rowBase = bid * 64 + wave * 16;
    int arow = rowBase + mrow;
    bool aok = arow < N_NODES;

    floatx4 acc[8];
#pragma unroll
    for (int t = 0; t < 8; ++t) acc[t] = (floatx4)0.f;

#pragma unroll
    for (int s = 0; s < 4; ++s) {
        union { short8 v; ushort u[8]; } af;
        if (A_FP32) {
            const float* A = (const float*)Av;
            if (aok) {
                const float* p = &A[(size_t)arow * HDIM + s * 32 + quad * 8];
#pragma unroll
                for (int j = 0; j < 8; ++j) af.u[j] = f2bf(p[j]);
            } else {
#pragma unroll
                for (int j = 0; j < 8; ++j) af.u[j] = 0;
            }
        } else {
            const ushort* A = (const ushort*)Av;
            if (aok) {
                af.v = *(const short8*)&A[(size_t)arow * HDIM + s * 32 + quad * 8];
            } else {
#pragma unroll
                for (int j = 0; j < 8; ++j) af.u[j] = 0;
            }
        }
#pragma unroll
        for (int t = 0; t < 8; ++t) {
            short8 bf = *(const short8*)&bfrag[(size_t)(((s * 8 + t) * 64) + lane) * 8];
            acc[t] = __builtin_amdgcn_mfma_f32_16x16x32_bf16(af.v, bf, acc[t], 0, 0, 0);
        }
    }
#pragma unroll
    for (int t = 0; t < 8; ++t) {
#pragma unroll
        for (int r = 0; r < 4; ++r) {
            int row = rowBase + quad * 4 + r;
            if (row < N_NODES) out[(size_t)row * HDIM + t * 16 + mrow] = f2bf(acc[t][r]);
        }
    }
}

// Fused: fill (independent) overlapped with layer-0 GEMM (independent).
__global__ __launch_bounds__(256) void fused0_kernel(
    const int* __restrict__ src, const int* __restrict__ dst, int* __restrict__ cnt,
    ushort* __restrict__ csr16, const float* __restrict__ x,
    const ushort* __restrict__ bfrag0, ushort* __restrict__ hw) {
    if (blockIdx.x < FILLB)
        fill_body(blockIdx.x, threadIdx.x, src, dst, cnt, csr16);
    else
        gemm_body<true>(blockIdx.x - FILLB, threadIdx.x, x, bfrag0, hw);
}

__global__ __launch_bounds__(256) void gemm_mfma_kernel(const ushort* __restrict__ A,
                                                        const ushort* __restrict__ bfrag,
                                                        ushort* __restrict__ out) {
    gemm_body<false>(blockIdx.x, threadIdx.x, A, bfrag, out);
}

// ---------------- Fused aggregate + self-loop + bias + LN (+GELU / +head) ----------------
// One wave per node; 2 edge-parity groups of 32 lanes; lane owns 4 columns (uint2).
// Weight factored: isd[n] * sum(isd[s]*hw[s]).
__global__ __launch_bounds__(256) void agg_ln_kernel(
    const uint2* __restrict__ hw2, const int* __restrict__ degcnt,
    const ushort* __restrict__ csr16, const float* __restrict__ isd,
    const float* __restrict__ ind, const float* __restrict__ conv_b,
    const float* __restrict__ ln_g, const float* __restrict__ ln_b,
    uint2* __restrict__ hout_bf, float* __restrict__ hout_f32,
    const float* __restrict__ head_w, const float* __restrict__ head_b,
    float* __restrict__ scores, int final_layer) {
    int wave = threadIdx.x >> 6;
    int lane = threadIdx.x & 63;
    int g = lane >> 5;   // edge-parity group
    int li = lane & 31;  // lane in group; owns cols li*4 .. li*4+3
    int n = blockIdx.x * 4 + wave;
    if (n >= N_NODES) return;
    int c = li * 4;

    float isd_n = isd[n], ind_n = ind[n];
    int rs = n * SEG;
    int deg = min(degcnt[n], SEG);

    float e0 = 0.f, e1 = 0.f, e2 = 0.f, e3 = 0.f;
    int sj = 0;
    float wj = 0.f;
    if (lane < deg) {
        sj = (int)csr16[rs + lane];
        wj = isd[sj];
    }
    // group g handles edges j+2t+g; lanes>=deg staged (0, 0.0f) so over-read
    // of the tail hits row 0 with weight 0 (harmless, idx never exceeds 63).
    for (int j = 0; j < deg; j += 8) {
#pragma unroll
        for (int t = 0; t < 4; ++t) {
            int idx = j + 2 * t + g;
            int s = __shfl(sj, idx);
            float w = __shfl(wj, idx);
            uint2 u = hw2[(size_t)s * 32 + li];
            float2 q0 = bf2f2(u.x), q1 = bf2f2(u.y);
            e0 = fmaf(q0.x, w, e0); e1 = fmaf(q0.y, w, e1);
            e2 = fmaf(q1.x, w, e2); e3 = fmaf(q1.y, w, e3);
        }
    }
    // combine the two parity groups (both halves end with full sums)
    e0 += __shfl_xor(e0, 32); e1 += __shfl_xor(e1, 32);
    e2 += __shfl_xor(e2, 32); e3 += __shfl_xor(e3, 32);

    uint2 hv = hw2[(size_t)n * 32 + li];
    float2 h0 = bf2f2(hv.x), h1 = bf2f2(hv.y);
    float4 cb = *(const float4*)&conv_b[c];
    float a0 = fmaf(e0, isd_n, fmaf(h0.x, ind_n, cb.x));
    float a1 = fmaf(e1, isd_n, fmaf(h0.y, ind_n, cb.y));
    float a2 = fmaf(e2, isd_n, fmaf(h1.x, ind_n, cb.z));
    float a3 = fmaf(e3, isd_n, fmaf(h1.y, ind_n, cb.w));

    // LayerNorm across 32 lanes (128 columns); both groups hold identical data
    float sum = a0 + a1 + a2 + a3;
#pragma unroll
    for (int o = 1; o < 32; o <<= 1) sum += __shfl_xor(sum, o);
    float mu = sum * (1.0f / HDIM);
    float d0 = a0 - mu, d1 = a1 - mu, d2 = a2 - mu, d3 = a3 - mu;
    float vs = d0 * d0 + d1 * d1 + d2 * d2 + d3 * d3;
#pragma unroll
    for (int o = 1; o < 32; o <<= 1) vs += __shfl_xor(vs, o);
    float rstd = rsqrtf(vs * (1.0f / HDIM) + LN_EPS);
    float4 gv = *(const float4*)&ln_g[c];
    float4 bv = *(const float4*)&ln_b[c];
    float y0 = fmaf(d0 * rstd, gv.x, bv.x);
    float y1 = fmaf(d1 * rstd, gv.y, bv.y);
    float y2 = fmaf(d2 * rstd, gv.z, bv.z);
    float y3 = fmaf(d3 * rstd, gv.w, bv.w);

    if (!final_layer) {
#define GELU(v) ((v) = 0.5f * (v) * (1.0f + erff((v) * 0.70710678118654752f)))
        GELU(y0); GELU(y1); GELU(y2); GELU(y3);
#undef GELU
        if (g == 0) {
            uint2 ov;
            ov.x = (unsigned)f2bf(y0) | ((unsigned)f2bf(y1) << 16);
            ov.y = (unsigned)f2bf(y2) | ((unsigned)f2bf(y3) << 16);
            hout_bf[(size_t)n * 32 + li] = ov;
        }
    } else {
        if (g == 0)
            *(float4*)&hout_f32[(size_t)n * HDIM + c] = make_float4(y0, y1, y2, y3);
        float4 hwv = *(const float4*)&head_w[c];
        float p = y0 * hwv.x + y1 * hwv.y + y2 * hwv.z + y3 * hwv.w;
#pragma unroll
        for (int o = 1; o < 32; o <<= 1) p += __shfl_xor(p, o);
        if (lane == 0) scores[n] = p + head_b[0];
    }
}

// ---------------- host ----------------

extern "C" void kernel_launch(void* const* d_in, const int* in_sizes, int n_in,
                              void* d_out, int out_size, void* d_ws, size_t ws_size,
                              hipStream_t stream) {
    const float* x      = (const float*)d_in[0];
    const int*   eidx   = (const int*)d_in[1];
    const float* conv_w = (const float*)d_in[2];
    const float* conv_b = (const float*)d_in[3];
    const float* ln_g   = (const float*)d_in[4];
    const float* ln_b   = (const float*)d_in[5];
    const float* head_w = (const float*)d_in[6];
    const float* head_b = (const float*)d_in[7];
    float* out = (float*)d_out;  // [N scores][N*H h]

    const int* src = eidx;
    const int* dst = eidx + N_EDGES;

    char* ws = (char*)d_ws;
    size_t o = 0;
    auto alloc = [&](size_t elems) {  // elems of 4 bytes
        void* p = ws + o * 4;
        o += (elems + 15) & ~(size_t)15;
        return p;
    };
    int*      cnt      = (int*)alloc(N_NODES);
    float*    isd      = (float*)alloc(N_NODES);
    float*    ind      = (float*)alloc(N_NODES);
    ushort*   csr16    = (ushort*)alloc((size_t)N_NODES * SEG / 2);
    ushort*   bfrag    = (ushort*)alloc(NLAYERS * 4 * 8 * 64 * 8 / 2);
    unsigned* hw       = (unsigned*)alloc((size_t)N_NODES * 64);   // bf16 N x 128
    unsigned* hbuf     = (unsigned*)alloc((size_t)N_NODES * 64);   // bf16 N x 128

    hipMemsetAsync(cnt, 0, N_NODES * sizeof(int), stream);
    bprep_kernel<<<(NLAYERS * 4 * 8 * 64 + 255) / 256, 256, 0, stream>>>(conv_w, bfrag);
    fused0_kernel<<<FILLB + GEMMB, 256, 0, stream>>>(src, dst, cnt, csr16, x, bfrag,
                                                     (ushort*)hw);
    isd_kernel<<<(N_NODES + 255) / 256, 256, 0, stream>>>(cnt, isd, ind);

    const unsigned* hin = hw;  // layer-0 hw already computed in fused0
    for (int l = 0; l < NLAYERS; ++l) {
        if (l > 0) {
            const ushort* bl = bfrag + (size_t)l * 4 * 8 * 64 * 8;
            gemm_mfma_kernel<<<GEMMB, 256, 0, stream>>>((const ushort*)hbuf, bl, (ushort*)hw);
        }
        int fin = (l == NLAYERS - 1) ? 1 : 0;
        agg_ln_kernel<<<(N_NODES + 3) / 4, 256, 0, stream>>>(
            (const uint2*)hw, cnt, csr16, isd, ind,
            conv_b + (size_t)l * HDIM, ln_g + (size_t)l * HDIM, ln_b + (size_t)l * HDIM,
            (uint2*)hbuf, out + N_NODES, head_w, head_b, out, fin);
    }
}